// Round 3
// baseline (529.003 us; speedup 1.0000x reference)
//
#include <hip/hip_runtime.h>

#define NN 50000
#define NE 150000
#define CAP 32   // bucket capacity; degrees Poisson(3), P(deg>=32) ~ 1e-20
#define GA 782   // grid of kernel A (= ceil(NN/64)); co-resident: <=4 blk/CU, 16 waves/CU
#define GB 256   // grid of kernel B; 1 blk/CU
#define NVB2 782 // conv2 virtual blocks = ceil(NN/NPB)
#define NPB 64

// device-scope arrive-and-spin grid barrier (all blocks co-resident by construction).
// release: threadfence (wbl2) before arrive; acquire: threadfence (inv) after observing target.
__device__ __forceinline__ void gbar(int* ctr, int target) {
    __syncthreads();
    if (threadIdx.x == 0) {
        __threadfence();
        __hip_atomic_fetch_add(ctr, 1, __ATOMIC_RELEASE, __HIP_MEMORY_SCOPE_AGENT);
        while (__hip_atomic_load(ctr, __ATOMIC_RELAXED, __HIP_MEMORY_SCOPE_AGENT) < target)
            __builtin_amdgcn_s_sleep(2);
        __threadfence();
    }
    __syncthreads();
}

// ================= Kernel A: scat -> node -> conv1 -> agg2 =================
__global__ __launch_bounds__(256, 4) void k_graph(
    const int* __restrict__ src, const int* __restrict__ dst,
    const float* __restrict__ x, const float* __restrict__ ef,
    const float* __restrict__ W1, const float* __restrict__ b1,
    int* cnt_in, int* cnt_out, int2* pbuck, int* obuck,
    float* din_arr, float* dsx4, float* c, float* h1s, float* agg2,
    int* bar)
{
    int tid = threadIdx.x;
    int gtid = blockIdx.x * 256 + tid;

    // ---- phase 1: degree count + bucket scatter ----
    if (gtid < NE) {
        int e = gtid;
        int s = src[e], d = dst[e];
        int si = atomicAdd(&cnt_in[d], 1) & (CAP - 1);
        pbuck[(size_t)d * CAP + si] = make_int2(e, s);
        int so = atomicAdd(&cnt_out[s], 1) & (CAP - 1);
        obuck[(size_t)s * CAP + so] = d;
    }
    gbar(&bar[0], GA);

    // ---- phase 2: node precompute (din table + dout-scaled features) ----
    if (gtid < NN) {
        int n = gtid;
        din_arr[n] = rsqrtf((float)(cnt_in[n] + 1));
        float dout = rsqrtf((float)(cnt_out[n] + 1));
        float4 xv = ((const float4*)x)[n];
        xv.x *= dout; xv.y *= dout; xv.z *= dout; xv.w *= dout;
        ((float4*)dsx4)[n] = xv;
    }
    gbar(&bar[1], GA);

    // ---- phase 3: conv1 gather (4 lanes/node) + c gather + 4->11 matvec/relu ----
    {
        int n = gtid >> 2, sub = gtid & 3;
        if (n < NN) {
            int ci = cnt_in[n], co = cnt_out[n];
            float din  = rsqrtf((float)(ci + 1));
            float dout = rsqrtf((float)(co + 1));
            float a0 = 0.f, a1 = 0.f, a2 = 0.f, a3 = 0.f;
            const int2* pb = pbuck + (size_t)n * CAP;
            for (int i = sub; i < ci; i += 4) {
                int2 p = pb[i];
                float4 u = ((const float4*)dsx4)[p.y];
                a0 += u.x; a1 += u.y; a2 += u.z; a3 += u.w;
            }
            float cacc = 0.f;
            const int* ob = obuck + (size_t)n * CAP;
            for (int i = sub; i < co; i += 4) cacc += din_arr[ob[i]];
            #pragma unroll
            for (int m = 1; m < 4; m <<= 1) {
                a0 += __shfl_xor(a0, m); a1 += __shfl_xor(a1, m);
                a2 += __shfl_xor(a2, m); a3 += __shfl_xor(a3, m);
                cacc += __shfl_xor(cacc, m);
            }
            float4 sv = ((const float4*)dsx4)[n];
            a0 += sv.x; a1 += sv.y; a2 += sv.z; a3 += sv.w;
            if (sub == 0) c[n] = cacc + din;
            #pragma unroll
            for (int jj = 0; jj < 3; jj++) {
                int j = sub + 4 * jj;
                if (j < 11) {
                    float y = a0 * W1[0 * 11 + j] + a1 * W1[1 * 11 + j] +
                              a2 * W1[2 * 11 + j] + a3 * W1[3 * 11 + j];
                    y = fmaxf(fmaf(y, din, b1[j]), 0.f);
                    h1s[(size_t)n * 11 + j] = y * dout;
                }
            }
        }
    }
    gbar(&bar[2], GA);

    // ---- phase 4: conv2 aggregation (flat (node, j) domain) ----
    for (int T = gtid; T < NN * 11; T += GA * 256) {
        int n = T / 11;
        int j = T - n * 11;
        int ci = cnt_in[n];
        const int2* pb = pbuck + (size_t)n * CAP;
        float acc = 0.f;
        for (int i = 0; i < ci; i++) {
            int2 p = pb[i];
            acc = fmaf(h1s[(size_t)p.y * 11 + j], ef[(size_t)p.x * 11 + j], acc);
        }
        agg2[T] = acc;
    }
}

// ================= Kernel B: conv2-reduce -> g -> heads1 -> heads2 -> final =================
__global__ __launch_bounds__(512, 4) void k_tail(
    const float* __restrict__ agg2, const float* __restrict__ W2, const float* __restrict__ b2,
    const float* __restrict__ c, const int* __restrict__ cnt_in, const int* __restrict__ cnt_out,
    const float* __restrict__ W3, const float* __restrict__ b3,
    const float* __restrict__ Wv1, const float* __restrict__ bv1,
    const float* __restrict__ Wv2, const float* __restrict__ bv2,
    const float* __restrict__ Wa1, const float* __restrict__ ba1,
    const float* __restrict__ Wa2, const float* __restrict__ ba2,
    float* t_part, float* t, float* g, float* hv_raw, float* ha_raw,
    float* a_acc, float* v, int* bar, float* out)
{
    __shared__ float tile[NPB * 11];
    __shared__ float din_sh[NPB], w_sh[NPB];
    __shared__ float sh[512];
    __shared__ int lastFlag;
    int tid = threadIdx.x, bid = blockIdx.x;

    // ---- phase 1: conv2 matvec+relu, weighted-mean partials (register acc, no atomics) ----
    {
        float w[11];
        #pragma unroll
        for (int j = 0; j < 11; j++) w[j] = W2[j * 512 + tid];
        float bias = b2[tid];
        float accT = 0.f;
        for (int vb = bid; vb < NVB2; vb += GB) {
            int n0 = vb * NPB;
            __syncthreads();   // protect previous iteration's tile
            for (int i = tid; i < NPB * 11; i += 512) {
                int gi = n0 * 11 + i;
                tile[i] = (gi < NN * 11) ? agg2[gi] : 0.f;
            }
            if (tid < NPB) {
                int node = n0 + tid;
                if (node < NN) {
                    din_sh[tid] = rsqrtf((float)(cnt_in[node] + 1));
                    w_sh[tid]   = c[node] * rsqrtf((float)(cnt_out[node] + 1)) * (1.0f / NN);
                } else { din_sh[tid] = 0.f; w_sh[tid] = 0.f; }
            }
            __syncthreads();
            for (int i = 0; i < NPB; i++) {
                float dot = 0.f;
                #pragma unroll
                for (int j = 0; j < 11; j++) dot = fmaf(tile[i * 11 + j], w[j], dot);
                float y = fmaxf(fmaf(dot, din_sh[i], bias), 0.f);
                accT = fmaf(w_sh[i], y, accT);
            }
        }
        t_part[bid * 512 + tid] = accT;
    }
    gbar(&bar[3], GB);

    // ---- phase 1b: t[ch] = sum over 256 block partials (16-way split) ----
    {
        int gt = bid * 512 + tid;
        if (gt < 16 * 512) {
            int c16 = gt >> 9, ch = gt & 511;
            float s = 0.f;
            #pragma unroll
            for (int b = 0; b < 16; b++) s += t_part[(c16 * 16 + b) * 512 + ch];
            atomicAdd(&t[ch], s);
        }
    }
    gbar(&bar[4], GB);

    // ---- phase 2: g = t @ W3 + b3 (k-split 16) ----
    if (bid < 32) {
        int oc = bid & 1, kc = bid >> 1;
        int o = oc * 512 + tid, k0 = kc * 32;
        float acc = (kc == 0) ? b3[o] : 0.f;
        #pragma unroll
        for (int k = 0; k < 32; k++)
            acc = fmaf(t[k0 + k], W3[(size_t)(k0 + k) * 1024 + o], acc);
        atomicAdd(&g[o], acc);
    }
    gbar(&bar[5], GB);

    // ---- phase 3: heads layer-1 partials ----
    if (bid < 128) {
        int oc = bid >> 4, kc = bid & 15;
        int idx = oc * 512 + tid;   // 0..4095
        int k0 = kc * 64;
        if (tid < 64) sh[tid] = g[k0 + tid];
        __syncthreads();
        const float* W; float* outp; int o;
        if (idx < 2048) { W = Wv1; outp = hv_raw; o = idx; }
        else            { W = Wa1; outp = ha_raw; o = idx - 2048; }
        float acc = 0.f;
        #pragma unroll 8
        for (int k = 0; k < 64; k++)
            acc = fmaf(sh[k], W[(size_t)(k0 + k) * 2048 + o], acc);
        atomicAdd(&outp[o], acc);
    }
    gbar(&bar[6], GB);

    // ---- phase 4: heads layer-2 (a partials + v) ----
    if (bid < 64) {
        int oc = bid >> 5, kc = bid & 31;
        int k0 = kc * 64;
        if (tid < 64) sh[tid] = fmaxf(ha_raw[k0 + tid] + ba1[k0 + tid], 0.f);
        __syncthreads();
        int o = oc * 512 + tid;   // 0..1023
        if (o < 1000) {
            float acc = 0.f;
            #pragma unroll 8
            for (int k = 0; k < 64; k++)
                acc = fmaf(sh[k], Wa2[(size_t)(k0 + k) * 1000 + o], acc);
            atomicAdd(&a_acc[o], acc);
        }
    } else if (bid == 64) {
        float acc = 0.f;
        for (int k = tid; k < 2048; k += 512)
            acc = fmaf(fmaxf(hv_raw[k] + bv1[k], 0.f), Wv2[k], acc);
        sh[tid] = acc;
        __syncthreads();
        for (int s2 = 256; s2 >= 1; s2 >>= 1) {
            if (tid < s2) sh[tid] += sh[tid + s2];
            __syncthreads();
        }
        if (tid == 0) *v = sh[0] + bv2[0];
    }

    // ---- final: last arriving block computes out = v + a - mean(a) ----
    __syncthreads();
    if (tid == 0) {
        __threadfence();
        int old = __hip_atomic_fetch_add(&bar[7], 1, __ATOMIC_ACQ_REL, __HIP_MEMORY_SCOPE_AGENT);
        lastFlag = (old == GB - 1) ? 1 : 0;
    }
    __syncthreads();
    if (!lastFlag) return;
    __threadfence();
    int i0 = tid, i1 = tid + 512;
    float ai0 = (i0 < 1000) ? a_acc[i0] + ba2[i0] : 0.f;
    float ai1 = (i1 < 1000) ? a_acc[i1] + ba2[i1] : 0.f;
    __syncthreads();
    sh[tid] = ai0 + ai1;
    __syncthreads();
    for (int s2 = 256; s2 >= 1; s2 >>= 1) {
        if (tid < s2) sh[tid] += sh[tid + s2];
        __syncthreads();
    }
    float amean = sh[0] * (1.0f / 1000.0f);
    float vv = *v;
    if (i0 < 1000) out[i0] = vv + ai0 - amean;
    if (i1 < 1000) out[i1] = vv + ai1 - amean;
}

extern "C" void kernel_launch(void* const* d_in, const int* in_sizes, int n_in,
                              void* d_out, int out_size, void* d_ws, size_t ws_size,
                              hipStream_t stream) {
    const float* x   = (const float*)d_in[0];
    const float* ef  = (const float*)d_in[1];
    const float* W1  = (const float*)d_in[2];
    const float* b1  = (const float*)d_in[3];
    const float* W2  = (const float*)d_in[4];
    const float* b2  = (const float*)d_in[5];
    const float* W3  = (const float*)d_in[6];
    const float* b3  = (const float*)d_in[7];
    const float* Wv1 = (const float*)d_in[8];
    const float* bv1 = (const float*)d_in[9];
    const float* Wv2 = (const float*)d_in[10];
    const float* bv2 = (const float*)d_in[11];
    const float* Wa1 = (const float*)d_in[12];
    const float* ba1 = (const float*)d_in[13];
    const float* Wa2 = (const float*)d_in[14];
    const float* ba2 = (const float*)d_in[15];
    const int*   src = (const int*)d_in[16];
    const int*   dst = (const int*)d_in[17];
    float* out = (float*)d_out;

    char* ws = (char*)d_ws;
    size_t off = 0;
    auto alloc = [&](size_t bytes) -> void* {
        void* p = ws + off;
        off = (off + bytes + 255) & ~(size_t)255;
        return p;
    };
    // --- zeroed region (counters + accumulators + barriers) ---
    int*   cnt_in  = (int*)  alloc(NN * 4);
    int*   cnt_out = (int*)  alloc(NN * 4);
    float* t       = (float*)alloc(512 * 4);
    float* g       = (float*)alloc(1024 * 4);
    float* hv_raw  = (float*)alloc(2048 * 4);
    float* ha_raw  = (float*)alloc(2048 * 4);
    float* a_acc   = (float*)alloc(1024 * 4);
    int*   bar     = (int*)  alloc(8 * 4);
    size_t zero_bytes = off;
    // --- non-zeroed scratch ---
    int2*  pbuck   = (int2*) alloc((size_t)NN * CAP * 8);
    int*   obuck   = (int*)  alloc((size_t)NN * CAP * 4);
    float* din_arr = (float*)alloc(NN * 4);
    float* dsx4    = (float*)alloc((size_t)NN * 16);
    float* c       = (float*)alloc(NN * 4);
    float* h1s     = (float*)alloc((size_t)NN * 11 * 4);
    float* agg2    = (float*)alloc((size_t)NN * 11 * 4);
    float* t_part  = (float*)alloc((size_t)GB * 512 * 4);
    float* v       = (float*)alloc(256);

    hipMemsetAsync(d_ws, 0, zero_bytes, stream);

    k_graph<<<GA, 256, 0, stream>>>(src, dst, x, ef, W1, b1,
                                    cnt_in, cnt_out, pbuck, obuck,
                                    din_arr, dsx4, c, h1s, agg2, bar);
    k_tail<<<GB, 512, 0, stream>>>(agg2, W2, b2, c, cnt_in, cnt_out,
                                   W3, b3, Wv1, bv1, Wv2, bv2, Wa1, ba1, Wa2, ba2,
                                   t_part, t, g, hv_raw, ha_raw, a_acc, v, bar, out);
}

// Round 4
// 200.459 us; speedup vs baseline: 2.6390x; 2.6390x over previous
//
#include <hip/hip_runtime.h>

#define NN 50000
#define NE 150000
#define CAP 32    // bucket capacity; degrees Poisson(3), P(deg>=32) ~ 1e-20
#define NPB 64
#define NVB2 782  // ceil(NN/NPB)
#define GC2 128   // conv2_reduce grid (atomic-free partials)

// ---------- K1: fused degree-count + bucket scatter ----------
__global__ __launch_bounds__(256) void k_scat(const int* __restrict__ src,
                                              const int* __restrict__ dst,
                                              int* __restrict__ cnt_in,
                                              int* __restrict__ cnt_out,
                                              int2* __restrict__ pbuck,
                                              int* __restrict__ obuck) {
    int e = blockIdx.x * 256 + threadIdx.x;
    if (e >= NE) return;
    int s = src[e], d = dst[e];
    int si = atomicAdd(&cnt_in[d], 1) & (CAP - 1);
    pbuck[(size_t)d * CAP + si] = make_int2(e, s);
    int so = atomicAdd(&cnt_out[s], 1) & (CAP - 1);
    obuck[(size_t)s * CAP + so] = d;
}

// ---------- K2: conv1 gather (4 lanes/node) + c gather + 4->11 matvec/relu ----------
// k_node folded in: degree scales computed on the fly from cnt arrays.
__global__ __launch_bounds__(256) void k_conv1c(const int* __restrict__ cnt_in,
                                                const int* __restrict__ cnt_out,
                                                const int2* __restrict__ pbuck,
                                                const int* __restrict__ obuck,
                                                const float* __restrict__ x,
                                                const float* __restrict__ W1,
                                                const float* __restrict__ b1,
                                                float* __restrict__ h1s,
                                                float* __restrict__ c) {
    int gtid = blockIdx.x * 256 + threadIdx.x;
    int n = gtid >> 2, sub = gtid & 3;
    if (n >= NN) return;
    int ci = cnt_in[n], co = cnt_out[n];
    float din  = rsqrtf((float)(ci + 1));
    float dout = rsqrtf((float)(co + 1));
    float a0 = 0.f, a1 = 0.f, a2 = 0.f, a3 = 0.f;
    const int2* pb = pbuck + (size_t)n * CAP;
    for (int i = sub; i < ci; i += 4) {
        int2 p = pb[i];                       // (e, s)
        float os = rsqrtf((float)(cnt_out[p.y] + 1));
        float4 u = ((const float4*)x)[p.y];
        a0 = fmaf(u.x, os, a0); a1 = fmaf(u.y, os, a1);
        a2 = fmaf(u.z, os, a2); a3 = fmaf(u.w, os, a3);
    }
    float cacc = 0.f;
    const int* ob = obuck + (size_t)n * CAP;
    for (int i = sub; i < co; i += 4) cacc += rsqrtf((float)(cnt_in[ob[i]] + 1));
    #pragma unroll
    for (int m = 1; m < 4; m <<= 1) {
        a0 += __shfl_xor(a0, m); a1 += __shfl_xor(a1, m);
        a2 += __shfl_xor(a2, m); a3 += __shfl_xor(a3, m);
        cacc += __shfl_xor(cacc, m);
    }
    float4 sv = ((const float4*)x)[n];        // self-loop term
    a0 = fmaf(sv.x, dout, a0); a1 = fmaf(sv.y, dout, a1);
    a2 = fmaf(sv.z, dout, a2); a3 = fmaf(sv.w, dout, a3);
    if (sub == 0) c[n] = cacc + din;          // self-loop contributes din
    #pragma unroll
    for (int jj = 0; jj < 3; jj++) {
        int j = sub + 4 * jj;
        if (j < 11) {
            float y = a0 * W1[0 * 11 + j] + a1 * W1[1 * 11 + j] +
                      a2 * W1[2 * 11 + j] + a3 * W1[3 * 11 + j];
            y = fmaxf(fmaf(y, din, b1[j]), 0.f);
            h1s[(size_t)n * 11 + j] = y * dout;
        }
    }
}

// ---------- K3: conv2 aggregation via pair-bucket gather ----------
__global__ __launch_bounds__(256) void k_agg2(const int* __restrict__ cnt_in,
                                              const int2* __restrict__ pbuck,
                                              const float* __restrict__ h1s,
                                              const float* __restrict__ ef,
                                              float* __restrict__ agg2) {
    int tid = threadIdx.x;
    if (tid >= 253) return;
    int q = tid / 11;
    int n = blockIdx.x * 23 + q;
    int j = tid - q * 11;
    if (n >= NN) return;
    int ci = cnt_in[n];
    const int2* pb = pbuck + (size_t)n * CAP;
    float acc = 0.f;
    for (int i = 0; i < ci; i++) {
        int2 p = pb[i];
        acc = fmaf(h1s[(size_t)p.y * 11 + j], ef[(size_t)p.x * 11 + j], acc);
    }
    agg2[(size_t)n * 11 + j] = acc;
}

// ---------- K4: conv2 matvec+relu + weighted-mean partials (atomic-free) ----------
__global__ __launch_bounds__(512) void k_conv2_reduce(const float* __restrict__ agg2,
                                                      const float* __restrict__ W2,
                                                      const float* __restrict__ b2,
                                                      const float* __restrict__ c,
                                                      const int* __restrict__ cnt_in,
                                                      const int* __restrict__ cnt_out,
                                                      float* __restrict__ t_part) {
    __shared__ float tile[NPB * 11];
    __shared__ float din_sh[NPB], w_sh[NPB];
    int tid = threadIdx.x, bid = blockIdx.x;
    float w[11];
    #pragma unroll
    for (int j = 0; j < 11; j++) w[j] = W2[j * 512 + tid];
    float bias = b2[tid];
    float accT = 0.f;
    for (int vb = bid; vb < NVB2; vb += GC2) {
        int n0 = vb * NPB;
        __syncthreads();   // protect previous iteration's tile
        for (int i = tid; i < NPB * 11; i += 512) {
            int gi = n0 * 11 + i;
            tile[i] = (gi < NN * 11) ? agg2[gi] : 0.f;
        }
        if (tid < NPB) {
            int node = n0 + tid;
            if (node < NN) {
                din_sh[tid] = rsqrtf((float)(cnt_in[node] + 1));
                w_sh[tid]   = c[node] * rsqrtf((float)(cnt_out[node] + 1)) * (1.0f / NN);
            } else { din_sh[tid] = 0.f; w_sh[tid] = 0.f; }
        }
        __syncthreads();
        for (int i = 0; i < NPB; i++) {
            float dot = 0.f;
            #pragma unroll
            for (int j = 0; j < 11; j++) dot = fmaf(tile[i * 11 + j], w[j], dot);
            float y = fmaxf(fmaf(dot, din_sh[i], bias), 0.f);
            accT = fmaf(w_sh[i], y, accT);
        }
    }
    t_part[bid * 512 + tid] = accT;
}

// ---------- K5: g_part[kc][o] = t_slice @ W3 (+ b3 on kc==0); no atomics ----------
__global__ __launch_bounds__(256) void k_g(const float* __restrict__ t_part,
                                           const float* __restrict__ W3,
                                           const float* __restrict__ b3,
                                           float* __restrict__ g_part) {
    __shared__ float red[256];
    __shared__ float ts[32];
    int b = blockIdx.x;          // 64 = 4 oc x 16 kc
    int oc = b & 3, kc = b >> 2;
    int tid = threadIdx.x;
    int k0 = kc * 32;
    // reduce t[k0 + ch] over 128 block partials: 8 groups of 16
    {
        int ch = tid & 31, grp = tid >> 5;   // grp 0..7
        float s = 0.f;
        #pragma unroll
        for (int p = 0; p < 16; p++)
            s += t_part[(grp * 16 + p) * 512 + k0 + ch];
        red[tid] = s;
        __syncthreads();
        if (tid < 32) {
            float s2 = 0.f;
            #pragma unroll
            for (int gp = 0; gp < 8; gp++) s2 += red[gp * 32 + tid];
            ts[tid] = s2;
        }
        __syncthreads();
    }
    int o = oc * 256 + tid;
    float acc = (kc == 0) ? b3[o] : 0.f;
    #pragma unroll 8
    for (int k = 0; k < 32; k++) acc = fmaf(ts[k], W3[(size_t)(k0 + k) * 1024 + o], acc);
    g_part[kc * 1024 + o] = acc;
}

// ---------- K6: head layer-1 partials (g summed from g_part; no atomics) ----------
// h_part[kc][0..2047] = hv partial, h_part[kc][2048..4095] = ha partial
__global__ __launch_bounds__(256) void k_heads1(const float* __restrict__ g_part,
                                                const float* __restrict__ Wv1,
                                                const float* __restrict__ Wa1,
                                                float* __restrict__ h_part) {
    __shared__ float red[256];
    __shared__ float gs[64];
    int b = blockIdx.x;
    int oc = b >> 4, kc = b & 15;
    int tid = threadIdx.x;
    int k0 = kc * 64;
    // gs[i] = sum over 16 g_part slices of g[k0+i]
    {
        int ch = tid & 63, grp = tid >> 6;   // grp 0..3
        float s = 0.f;
        #pragma unroll
        for (int p = 0; p < 4; p++)
            s += g_part[(grp * 4 + p) * 1024 + k0 + ch];
        red[tid] = s;
        __syncthreads();
        if (tid < 64) gs[tid] = red[tid] + red[64 + tid] + red[128 + tid] + red[192 + tid];
        __syncthreads();
    }
    int idx = oc * 256 + tid;  // 0..4095
    const float* W; int o;
    if (idx < 2048) { W = Wv1; o = idx; }
    else            { W = Wa1; o = idx - 2048; }
    float acc = 0.f;
    #pragma unroll 8
    for (int k = 0; k < 64; k++) acc = fmaf(gs[k], W[(size_t)(k0 + k) * 2048 + o], acc);
    h_part[kc * 4096 + idx] = acc;
}

// ---------- K7: head layer-2 + fused final (exit-style lastFlag; no spinning) ----------
__global__ __launch_bounds__(256) void k_heads2f(const float* __restrict__ h_part,
                                                 const float* __restrict__ bv1,
                                                 const float* __restrict__ ba1,
                                                 const float* __restrict__ Wv2,
                                                 const float* __restrict__ bv2,
                                                 const float* __restrict__ Wa2,
                                                 const float* __restrict__ ba2,
                                                 float* __restrict__ a_acc,
                                                 float* __restrict__ v,
                                                 int* __restrict__ done,
                                                 float* __restrict__ out) {
    __shared__ float sh[256];
    __shared__ int lastFlag;
    int b = blockIdx.x;
    int tid = threadIdx.x;
    if (b < 128) {
        int oc = b >> 5, kc = b & 31;   // oc 0..3, kc 0..31
        int k0 = kc * 64;
        if (tid < 64) {
            float ha = 0.f;
            #pragma unroll
            for (int p = 0; p < 16; p++) ha += h_part[p * 4096 + 2048 + k0 + tid];
            sh[tid] = fmaxf(ha + ba1[k0 + tid], 0.f);
        }
        __syncthreads();
        int o = oc * 256 + tid;  // 0..1023
        if (o < 1000) {
            float acc = 0.f;
            #pragma unroll 8
            for (int k = 0; k < 64; k++)
                acc = fmaf(sh[k], Wa2[(size_t)(k0 + k) * 1000 + o], acc);
            atomicAdd(&a_acc[o], acc);
        }
    } else {
        float acc = 0.f;
        for (int k = tid; k < 2048; k += 256) {
            float hv = 0.f;
            #pragma unroll
            for (int p = 0; p < 16; p++) hv += h_part[p * 4096 + k];
            acc = fmaf(fmaxf(hv + bv1[k], 0.f), Wv2[k], acc);
        }
        sh[tid] = acc;
        __syncthreads();
        for (int s2 = 128; s2 >= 1; s2 >>= 1) {
            if (tid < s2) sh[tid] += sh[tid + s2];
            __syncthreads();
        }
        if (tid == 0) *v = sh[0] + bv2[0];
    }
    // exit-style completion: last arriving block computes the final output
    __syncthreads();
    if (tid == 0) {
        __threadfence();
        int old = atomicAdd(done, 1);
        lastFlag = (old == 128) ? 1 : 0;
    }
    __syncthreads();
    if (!lastFlag) return;
    __threadfence();
    float ai[4];
    float lsum = 0.f;
    #pragma unroll
    for (int k = 0; k < 4; k++) {
        int idx = tid + k * 256;
        float val = (idx < 1000) ? a_acc[idx] + ba2[idx] : 0.f;
        ai[k] = val;
        lsum += val;
    }
    __syncthreads();
    sh[tid] = lsum;
    __syncthreads();
    for (int s2 = 128; s2 >= 1; s2 >>= 1) {
        if (tid < s2) sh[tid] += sh[tid + s2];
        __syncthreads();
    }
    float amean = sh[0] * (1.0f / 1000.0f);
    float vv = *v;
    #pragma unroll
    for (int k = 0; k < 4; k++) {
        int idx = tid + k * 256;
        if (idx < 1000) out[idx] = vv + ai[k] - amean;
    }
}

extern "C" void kernel_launch(void* const* d_in, const int* in_sizes, int n_in,
                              void* d_out, int out_size, void* d_ws, size_t ws_size,
                              hipStream_t stream) {
    const float* x   = (const float*)d_in[0];
    const float* ef  = (const float*)d_in[1];
    const float* W1  = (const float*)d_in[2];
    const float* b1  = (const float*)d_in[3];
    const float* W2  = (const float*)d_in[4];
    const float* b2  = (const float*)d_in[5];
    const float* W3  = (const float*)d_in[6];
    const float* b3  = (const float*)d_in[7];
    const float* Wv1 = (const float*)d_in[8];
    const float* bv1 = (const float*)d_in[9];
    const float* Wv2 = (const float*)d_in[10];
    const float* bv2 = (const float*)d_in[11];
    const float* Wa1 = (const float*)d_in[12];
    const float* ba1 = (const float*)d_in[13];
    const float* Wa2 = (const float*)d_in[14];
    const float* ba2 = (const float*)d_in[15];
    const int*   src = (const int*)d_in[16];
    const int*   dst = (const int*)d_in[17];
    float* out = (float*)d_out;

    char* ws = (char*)d_ws;
    size_t off = 0;
    auto alloc = [&](size_t bytes) -> void* {
        void* p = ws + off;
        off = (off + bytes + 255) & ~(size_t)255;
        return p;
    };
    // --- zeroed region (counters + the only remaining atomic accumulator) ---
    int*   cnt_in  = (int*)  alloc(NN * 4);
    int*   cnt_out = (int*)  alloc(NN * 4);
    float* a_acc   = (float*)alloc(1024 * 4);
    int*   done    = (int*)  alloc(256);
    size_t zero_bytes = off;
    // --- non-zeroed scratch ---
    int2*  pbuck   = (int2*) alloc((size_t)NN * CAP * 8);
    int*   obuck   = (int*)  alloc((size_t)NN * CAP * 4);
    float* c       = (float*)alloc(NN * 4);
    float* h1s     = (float*)alloc((size_t)NN * 11 * 4);
    float* agg2    = (float*)alloc((size_t)NN * 11 * 4);
    float* t_part  = (float*)alloc((size_t)GC2 * 512 * 4);
    float* g_part  = (float*)alloc((size_t)16 * 1024 * 4);
    float* h_part  = (float*)alloc((size_t)16 * 4096 * 4);
    float* v       = (float*)alloc(256);

    hipMemsetAsync(d_ws, 0, zero_bytes, stream);

    k_scat<<<(NE + 255) / 256, 256, 0, stream>>>(src, dst, cnt_in, cnt_out, pbuck, obuck);
    k_conv1c<<<(NN + 63) / 64, 256, 0, stream>>>(cnt_in, cnt_out, pbuck, obuck,
                                                 x, W1, b1, h1s, c);
    k_agg2<<<(NN + 22) / 23, 256, 0, stream>>>(cnt_in, pbuck, h1s, ef, agg2);
    k_conv2_reduce<<<GC2, 512, 0, stream>>>(agg2, W2, b2, c, cnt_in, cnt_out, t_part);
    k_g<<<64, 256, 0, stream>>>(t_part, W3, b3, g_part);
    k_heads1<<<256, 256, 0, stream>>>(g_part, Wv1, Wa1, h_part);
    k_heads2f<<<129, 256, 0, stream>>>(h_part, bv1, ba1, Wv2, bv2, Wa2, ba2,
                                       a_acc, v, done, out);
}

// Round 5
// 188.806 us; speedup vs baseline: 2.8018x; 1.0617x over previous
//
#include <hip/hip_runtime.h>

#define NN 50000
#define NE 150000
#define CAP 32    // bucket capacity; degrees Poisson(3), P(deg>=32) ~ 1e-20
#define NPB 64

// ---------- K1: fused degree-count + bucket scatter ----------
__global__ __launch_bounds__(256) void k_scat(const int* __restrict__ src,
                                              const int* __restrict__ dst,
                                              int* __restrict__ cnt_in,
                                              int* __restrict__ cnt_out,
                                              int2* __restrict__ pbuck,
                                              int* __restrict__ obuck) {
    int e = blockIdx.x * 256 + threadIdx.x;
    if (e >= NE) return;
    int s = src[e], d = dst[e];
    int si = atomicAdd(&cnt_in[d], 1) & (CAP - 1);
    pbuck[(size_t)d * CAP + si] = make_int2(e, s);
    int so = atomicAdd(&cnt_out[s], 1) & (CAP - 1);
    obuck[(size_t)s * CAP + so] = d;
}

// ---------- K2: per-node precompute: din table + dout-prescaled features ----------
__global__ __launch_bounds__(256) void k_node(const float* __restrict__ x,
                                              const int* __restrict__ cnt_in,
                                              const int* __restrict__ cnt_out,
                                              float* __restrict__ din_arr,
                                              float4* __restrict__ dsx4) {
    int n = blockIdx.x * 256 + threadIdx.x;
    if (n >= NN) return;
    din_arr[n] = rsqrtf((float)(cnt_in[n] + 1));
    float dout = rsqrtf((float)(cnt_out[n] + 1));
    float4 xv = ((const float4*)x)[n];
    xv.x *= dout; xv.y *= dout; xv.z *= dout; xv.w *= dout;
    dsx4[n] = xv;
}

// ---------- K3: conv1 gather (4 lanes/node) + c gather + 4->11 matvec/relu ----------
__global__ __launch_bounds__(256) void k_conv1c(const int* __restrict__ cnt_in,
                                                const int* __restrict__ cnt_out,
                                                const int2* __restrict__ pbuck,
                                                const int* __restrict__ obuck,
                                                const float* __restrict__ din_arr,
                                                const float4* __restrict__ dsx4,
                                                const float* __restrict__ W1,
                                                const float* __restrict__ b1,
                                                float* __restrict__ h1s,
                                                float* __restrict__ c) {
    int tid = threadIdx.x;
    int n = blockIdx.x * 64 + (tid >> 2);
    int sub = tid & 3;
    if (n >= NN) return;
    int ci = cnt_in[n], co = cnt_out[n];
    float din  = rsqrtf((float)(ci + 1));
    float dout = rsqrtf((float)(co + 1));
    float a0 = 0.f, a1 = 0.f, a2 = 0.f, a3 = 0.f;
    const int2* pb = pbuck + (size_t)n * CAP;
    for (int i = sub; i < ci; i += 4) {
        int2 p = pb[i];                  // (e, s); only s needed here
        float4 u = dsx4[p.y];
        a0 += u.x; a1 += u.y; a2 += u.z; a3 += u.w;
    }
    float cacc = 0.f;
    const int* ob = obuck + (size_t)n * CAP;
    for (int i = sub; i < co; i += 4) cacc += din_arr[ob[i]];
    #pragma unroll
    for (int m = 1; m < 4; m <<= 1) {
        a0 += __shfl_xor(a0, m); a1 += __shfl_xor(a1, m);
        a2 += __shfl_xor(a2, m); a3 += __shfl_xor(a3, m);
        cacc += __shfl_xor(cacc, m);
    }
    float4 sv = dsx4[n];                 // self-loop term (already dout-scaled)
    a0 += sv.x; a1 += sv.y; a2 += sv.z; a3 += sv.w;
    if (sub == 0) c[n] = cacc + din;     // self-loop contributes din
    #pragma unroll
    for (int jj = 0; jj < 3; jj++) {
        int j = sub + 4 * jj;
        if (j < 11) {
            float y = a0 * W1[0 * 11 + j] + a1 * W1[1 * 11 + j] +
                      a2 * W1[2 * 11 + j] + a3 * W1[3 * 11 + j];
            y = fmaxf(fmaf(y, din, b1[j]), 0.f);
            h1s[(size_t)n * 11 + j] = y * dout;
        }
    }
}

// ---------- K4: FUSED conv2 aggregation (bucket gather -> LDS) + matvec/relu
//              + weighted-mean reduction into t[512] (atomics, proven cheap) ----------
__global__ __launch_bounds__(512) void k_agg2conv2(const int* __restrict__ cnt_in,
                                                   const int* __restrict__ cnt_out,
                                                   const int2* __restrict__ pbuck,
                                                   const float* __restrict__ h1s,
                                                   const float* __restrict__ ef,
                                                   const float* __restrict__ W2,
                                                   const float* __restrict__ b2,
                                                   const float* __restrict__ c,
                                                   float* __restrict__ t) {
    __shared__ float tile[NPB * 11];
    __shared__ float din_sh[NPB], w_sh[NPB];
    int tid = threadIdx.x;
    int n0 = blockIdx.x * NPB;
    // phase A: gather the agg2 tile (identical access pattern to round-2 k_agg2)
    for (int idx = tid; idx < NPB * 11; idx += 512) {
        int q = idx / 11, j = idx - q * 11;
        int n = n0 + q;
        float acc = 0.f;
        if (n < NN) {
            int ci = cnt_in[n];
            const int2* pb = pbuck + (size_t)n * CAP;
            for (int i = 0; i < ci; i++) {
                int2 p = pb[i];          // (e, s)
                acc = fmaf(h1s[(size_t)p.y * 11 + j], ef[(size_t)p.x * 11 + j], acc);
            }
        }
        tile[idx] = acc;
    }
    if (tid < NPB) {
        int node = n0 + tid;
        if (node < NN) {
            din_sh[tid] = rsqrtf((float)(cnt_in[node] + 1));
            w_sh[tid]   = c[node] * rsqrtf((float)(cnt_out[node] + 1)) * (1.0f / NN);
        } else { din_sh[tid] = 0.f; w_sh[tid] = 0.f; }
    }
    __syncthreads();
    // phase B: per-channel matvec + relu + weighted accumulation
    float w[11];
    #pragma unroll
    for (int j = 0; j < 11; j++) w[j] = W2[j * 512 + tid];
    float bias = b2[tid];
    float acc = 0.f;
    for (int i = 0; i < NPB; i++) {
        float dot = 0.f;
        #pragma unroll
        for (int j = 0; j < 11; j++) dot = fmaf(tile[i * 11 + j], w[j], dot);
        float y = fmaxf(fmaf(dot, din_sh[i], bias), 0.f);
        acc = fmaf(w_sh[i], y, acc);
    }
    atomicAdd(&t[tid], acc);
}

// ---------- K5: FUSED g-slice recompute + head layer-1 partials ----------
// block (oc 0..15, kc 0..15): computes the FULL g[k0..k0+63] slice from t,
// then its heads1 k-chunk. W3 slice read 16x redundantly (128KB/block).
__global__ __launch_bounds__(256) void k_heads1g(const float* __restrict__ t,
                                                 const float* __restrict__ W3,
                                                 const float* __restrict__ b3,
                                                 const float* __restrict__ Wv1,
                                                 const float* __restrict__ Wa1,
                                                 float* __restrict__ hv_raw,
                                                 float* __restrict__ ha_raw) {
    __shared__ float ts[512];
    __shared__ float gpart[256];
    __shared__ float gs[64];
    int b = blockIdx.x;
    int oc = b >> 4, kc = b & 15;
    int tid = threadIdx.x;
    int k0 = kc * 64;
    ts[tid] = t[tid];
    ts[tid + 256] = t[tid + 256];
    __syncthreads();
    // g[k0+i] = b3[k0+i] + sum_k ts[k] * W3[k][k0+i]; i = tid&63, kpart = tid>>6
    {
        int i = tid & 63, kp = tid >> 6;
        float p = 0.f;
        int kb = kp * 128;
        #pragma unroll 8
        for (int k = 0; k < 128; k++)
            p = fmaf(ts[kb + k], W3[(size_t)(kb + k) * 1024 + k0 + i], p);
        gpart[tid] = p;
        __syncthreads();
        if (tid < 64)
            gs[tid] = b3[k0 + tid] + gpart[tid] + gpart[64 + tid] +
                      gpart[128 + tid] + gpart[192 + tid];
        __syncthreads();
    }
    int idx = oc * 256 + tid;  // 0..4095
    const float* W; float* outp; int o;
    if (idx < 2048) { W = Wv1; outp = hv_raw; o = idx; }
    else            { W = Wa1; outp = ha_raw; o = idx - 2048; }
    float acc = 0.f;
    #pragma unroll 8
    for (int k = 0; k < 64; k++)
        acc = fmaf(gs[k], W[(size_t)(k0 + k) * 2048 + o], acc);
    atomicAdd(&outp[o], acc);
}

// ---------- K6: head layer-2 + fused final (exit-style lastFlag; no spinning) ----------
__global__ __launch_bounds__(256) void k_heads2f(const float* __restrict__ hv_raw,
                                                 const float* __restrict__ bv1,
                                                 const float* __restrict__ ha_raw,
                                                 const float* __restrict__ ba1,
                                                 const float* __restrict__ Wv2,
                                                 const float* __restrict__ bv2,
                                                 const float* __restrict__ Wa2,
                                                 const float* __restrict__ ba2,
                                                 float* __restrict__ a_acc,
                                                 float* __restrict__ v,
                                                 int* __restrict__ done,
                                                 float* __restrict__ out) {
    __shared__ float sh[256];
    __shared__ int lastFlag;
    int b = blockIdx.x;
    int tid = threadIdx.x;
    if (b < 128) {
        int oc = b >> 5, kc = b & 31;   // oc 0..3, kc 0..31
        int k0 = kc * 64;
        if (tid < 64) sh[tid] = fmaxf(ha_raw[k0 + tid] + ba1[k0 + tid], 0.f);
        __syncthreads();
        int o = oc * 256 + tid;  // 0..1023
        if (o < 1000) {
            float acc = 0.f;
            #pragma unroll 8
            for (int k = 0; k < 64; k++)
                acc = fmaf(sh[k], Wa2[(size_t)(k0 + k) * 1000 + o], acc);
            atomicAdd(&a_acc[o], acc);
        }
    } else {
        float acc = 0.f;
        for (int k = tid; k < 2048; k += 256)
            acc = fmaf(fmaxf(hv_raw[k] + bv1[k], 0.f), Wv2[k], acc);
        sh[tid] = acc;
        __syncthreads();
        for (int s2 = 128; s2 >= 1; s2 >>= 1) {
            if (tid < s2) sh[tid] += sh[tid + s2];
            __syncthreads();
        }
        if (tid == 0) *v = sh[0] + bv2[0];
    }
    // exit-style completion: last arriving block computes the final output
    __syncthreads();
    if (tid == 0) {
        __threadfence();
        int old = atomicAdd(done, 1);
        lastFlag = (old == 128) ? 1 : 0;
    }
    __syncthreads();
    if (!lastFlag) return;
    __threadfence();
    float ai[4];
    float lsum = 0.f;
    #pragma unroll
    for (int k = 0; k < 4; k++) {
        int idx = tid + k * 256;
        float val = (idx < 1000) ? a_acc[idx] + ba2[idx] : 0.f;
        ai[k] = val;
        lsum += val;
    }
    __syncthreads();
    sh[tid] = lsum;
    __syncthreads();
    for (int s2 = 128; s2 >= 1; s2 >>= 1) {
        if (tid < s2) sh[tid] += sh[tid + s2];
        __syncthreads();
    }
    float amean = sh[0] * (1.0f / 1000.0f);
    float vv = *v;
    #pragma unroll
    for (int k = 0; k < 4; k++) {
        int idx = tid + k * 256;
        if (idx < 1000) out[idx] = vv + ai[k] - amean;
    }
}

extern "C" void kernel_launch(void* const* d_in, const int* in_sizes, int n_in,
                              void* d_out, int out_size, void* d_ws, size_t ws_size,
                              hipStream_t stream) {
    const float* x   = (const float*)d_in[0];
    const float* ef  = (const float*)d_in[1];
    const float* W1  = (const float*)d_in[2];
    const float* b1  = (const float*)d_in[3];
    const float* W2  = (const float*)d_in[4];
    const float* b2  = (const float*)d_in[5];
    const float* W3  = (const float*)d_in[6];
    const float* b3  = (const float*)d_in[7];
    const float* Wv1 = (const float*)d_in[8];
    const float* bv1 = (const float*)d_in[9];
    const float* Wv2 = (const float*)d_in[10];
    const float* bv2 = (const float*)d_in[11];
    const float* Wa1 = (const float*)d_in[12];
    const float* ba1 = (const float*)d_in[13];
    const float* Wa2 = (const float*)d_in[14];
    const float* ba2 = (const float*)d_in[15];
    const int*   src = (const int*)d_in[16];
    const int*   dst = (const int*)d_in[17];
    float* out = (float*)d_out;

    char* ws = (char*)d_ws;
    size_t off = 0;
    auto alloc = [&](size_t bytes) -> void* {
        void* p = ws + off;
        off = (off + bytes + 255) & ~(size_t)255;
        return p;
    };
    // --- zeroed region (counters + accumulators) ---
    int*   cnt_in  = (int*)  alloc(NN * 4);
    int*   cnt_out = (int*)  alloc(NN * 4);
    float* t       = (float*)alloc(512 * 4);
    float* hv_raw  = (float*)alloc(2048 * 4);
    float* ha_raw  = (float*)alloc(2048 * 4);
    float* a_acc   = (float*)alloc(1024 * 4);
    int*   done    = (int*)  alloc(256);
    size_t zero_bytes = off;
    // --- non-zeroed scratch ---
    int2*  pbuck   = (int2*) alloc((size_t)NN * CAP * 8);
    int*   obuck   = (int*)  alloc((size_t)NN * CAP * 4);
    float* din_arr = (float*)alloc(NN * 4);
    float4* dsx4   = (float4*)alloc((size_t)NN * 16);
    float* c       = (float*)alloc(NN * 4);
    float* h1s     = (float*)alloc((size_t)NN * 11 * 4);
    float* v       = (float*)alloc(256);

    hipMemsetAsync(d_ws, 0, zero_bytes, stream);

    k_scat<<<(NE + 255) / 256, 256, 0, stream>>>(src, dst, cnt_in, cnt_out, pbuck, obuck);
    k_node<<<(NN + 255) / 256, 256, 0, stream>>>(x, cnt_in, cnt_out, din_arr, dsx4);
    k_conv1c<<<(NN + 63) / 64, 256, 0, stream>>>(cnt_in, cnt_out, pbuck, obuck,
                                                 din_arr, dsx4, W1, b1, h1s, c);
    k_agg2conv2<<<(NN + NPB - 1) / NPB, 512, 0, stream>>>(cnt_in, cnt_out, pbuck,
                                                          h1s, ef, W2, b2, c, t);
    k_heads1g<<<256, 256, 0, stream>>>(t, W3, b3, Wv1, Wa1, hv_raw, ha_raw);
    k_heads2f<<<129, 256, 0, stream>>>(hv_raw, bv1, ha_raw, ba1, Wv2, bv2, Wa2, ba2,
                                       a_acc, v, done, out);
}